// Round 6
// baseline (679.529 us; speedup 1.0000x reference)
//
#include <hip/hip_runtime.h>
#include <hip/hip_bf16.h>
#include <hip/hip_fp16.h>
#include <cstdint>
#include <cstddef>

#define H    50
#define G4   200      // 4*H gates
#define TT   256      // timesteps
#define BATCH 512
#define KDIM 144      // layer-0 input dim
#define ODIM 144      // FC output dim
#define XPLD 208      // XP row width: gate-interleaved p = kk*4+gate, kk padded to 52
#define WKP  160      // padded K for the xproj weight panel

typedef _Float16 half8  __attribute__((ext_vector_type(8)));
typedef _Float16 half4v __attribute__((ext_vector_type(4)));
typedef float    floatx4 __attribute__((ext_vector_type(4)));

__device__ __forceinline__ float sigm(float x) {
    return 1.0f / (1.0f + __expf(-x));
}
__device__ __forceinline__ float tanhx(float x) {
    float e = __expf(2.0f * x);
    return 1.0f - 2.0f / (e + 1.0f);
}

// ---------- Kernel 0: W_ih0 [200][144] fp32 -> Wf [208][160] f16, rows permuted
// to p = kk*4 + gate (XP columns come out gate-interleaved). ----------
__global__ __launch_bounds__(256) void wcvt(const float* __restrict__ W,
                                            _Float16* __restrict__ Wf) {
    const int idx = blockIdx.x * 256 + threadIdx.x;
    if (idx >= XPLD * WKP) return;
    const int p = idx / WKP, k = idx % WKP;
    const int kk = p >> 2, g = p & 3;
    const float v = (kk < H && k < KDIM) ? W[(size_t)(g * H + kk) * KDIM + k] : 0.0f;
    Wf[idx] = (_Float16)v;
}

// ---------- Kernel 1: XP[m][208] (f16) = X[m][144] @ Wf^T + bias0, MFMA ----------
// 2048 WGs x 256 thr. C is assembled in LDS (bias added in f32), then written to
// XP with fully coalesced 16B stores. bias0 = b_ih0 + b_hh0 permuted to p-space.
__global__ __launch_bounds__(256) void xproj(const float* __restrict__ X,
                                             const _Float16* __restrict__ Wf,
                                             const float* __restrict__ bih0,
                                             const float* __restrict__ bhh0,
                                             _Float16* __restrict__ XP) {
    __shared__ _Float16 ost[64][216];   // [m_local][p], 432B row (108 dwords)
    const int lane = threadIdx.x & 63;
    const int wv   = threadIdx.x >> 6;
    const int mrow = lane & 15;
    const int q    = lane >> 4;
    const int m0   = blockIdx.x * 64 + wv * 16;

    // per-lane bias values for its 13 C columns (p = n*16 + mrow)
    float bcol[13];
    #pragma unroll
    for (int n = 0; n < 13; ++n) {
        const int p = n * 16 + mrow;
        const int kk = p >> 2, g = p & 3;
        bcol[n] = (kk < H) ? (bih0[g * H + kk] + bhh0[g * H + kk]) : 0.0f;
    }

    floatx4 acc[13];
    #pragma unroll
    for (int n = 0; n < 13; ++n) acc[n] = (floatx4)(0.0f);

    #pragma unroll
    for (int s = 0; s < 5; ++s) {
        const int kbase = s * 32 + q * 8;
        half8 a;
        if (kbase + 7 < KDIM) {
            const float4 x0 = *(const float4*)&X[(size_t)(m0 + mrow) * KDIM + kbase];
            const float4 x1 = *(const float4*)&X[(size_t)(m0 + mrow) * KDIM + kbase + 4];
            a[0] = (_Float16)x0.x; a[1] = (_Float16)x0.y;
            a[2] = (_Float16)x0.z; a[3] = (_Float16)x0.w;
            a[4] = (_Float16)x1.x; a[5] = (_Float16)x1.y;
            a[6] = (_Float16)x1.z; a[7] = (_Float16)x1.w;
        } else {
            #pragma unroll
            for (int j = 0; j < 8; ++j) a[j] = (_Float16)0.0f;
        }
        #pragma unroll
        for (int n = 0; n < 13; ++n) {
            const half8 b = *(const half8*)&Wf[(size_t)(n * 16 + mrow) * WKP + s * 32 + q * 8];
            acc[n] = __builtin_amdgcn_mfma_f32_16x16x32_f16(a, b, acc[n], 0, 0, 0);
        }
    }
    // C layout: col p = n*16+mrow, row m = q*4 + r  -> scatter into LDS (+bias, f32)
    #pragma unroll
    for (int n = 0; n < 13; ++n) {
        #pragma unroll
        for (int r = 0; r < 4; ++r) {
            ost[wv * 16 + q * 4 + r][n * 16 + mrow] = (_Float16)(acc[n][r] + bcol[n]);
        }
    }
    __syncthreads();
    // coalesced write-out: 64 rows x 26 16B-chunks
    const int mbase = blockIdx.x * 64;
    for (int c = threadIdx.x; c < 64 * 26; c += 256) {
        const int m = c / 26, j = c - m * 26;
        const half8 v = *(const half8*)&ost[m][j * 8];
        *(half8*)&XP[(size_t)(mbase + m) * XPLD + j * 8] = v;
    }
}

// ---------- helpers to build lstm A-fragments (A: m = lane&15, k = q*8+j) ----------
__device__ __forceinline__ half8 make_a0(const float* __restrict__ Whh0,
                                         int kkA, int gate, int q, int s) {
    const float* r0 = Whh0 + (size_t)(gate * H + (kkA < H ? kkA : 0)) * H;
    half8 r;
    #pragma unroll
    for (int j = 0; j < 8; ++j) {
        const int k = s * 32 + q * 8 + j;
        r[j] = (_Float16)((kkA < H && k < H) ? r0[k] : 0.0f);
    }
    return r;
}
__device__ __forceinline__ half8 make_a1(const float* __restrict__ Wih1,
                                         const float* __restrict__ Whh1,
                                         const float* __restrict__ bih1,
                                         const float* __restrict__ bhh1,
                                         int kkA, int gate, int q, int s) {
    const int p = gate * H + (kkA < H ? kkA : 0);
    half8 r;
    #pragma unroll
    for (int j = 0; j < 8; ++j) {
        const int k = s * 32 + q * 8 + j;
        float v = 0.0f;
        if (kkA < H) {
            if (k < H)            v = Wih1[(size_t)p * H + k];
            else if (k < 2 * H)   v = Whh1[(size_t)p * H + (k - H)];
            else if (k == 100)    v = bih1[p] + bhh1[p];   // bias rides constant-1 B row
        }
        r[j] = (_Float16)v;
    }
    return r;
}

// ---------- Kernel 2: MFMA recurrence, 256 WGs x 512 thr, 2 batch rows/WG ----------
// Row space (512): [0,256) = L0 gates (p = kk*4+gate), [256,512) = L1 gates.
// K pad 128: k 0..49 = h0, 50..99 = h1, k=100 = constant 1.0 (bias1 channel).
// Wave w owns tiles {2w,2w+1} for both L0 (ksteps 0,1) and L1 (ksteps 0..3).
// A-frags forced resident: built from global once, round-tripped through LDS with
// barriers (two 48KB phases) -> compiler cannot rematerialize from global (R5 bug:
// 27GB FETCH). B double-buffered in LDS [buf][s][q][col][j]; hot read = lane*16,
// conflict-free. C regs are the 4 gates of one hidden unit -> in-register epilogue.
__global__ __launch_bounds__(512, 1) void lstm_mfma(
    const _Float16* __restrict__ XP,
    const float* __restrict__ Whh0,
    const float* __restrict__ Wih1,
    const float* __restrict__ Whh1,
    const float* __restrict__ bih1, const float* __restrict__ bhh1,
    const float* __restrict__ Wfc,  const float* __restrict__ bfc,
    float* __restrict__ out)
{
    const int b0   = blockIdx.x * 2;
    const int tid  = threadIdx.x;
    const int lane = tid & 63;
    const int w    = tid >> 6;       // wave 0..7
    const int col  = lane & 15;      // B col / C col (batch row for col<2)
    const int q    = lane >> 4;      // 0..3
    const int prow = lane & 15;      // A row within tile
    const int gate = prow & 3;

    __shared__ __align__(16) unsigned char smem[49152];
    half8* stg = (half8*)smem;       // staging: [512][6]

    const int kkA0 = 8 * w + 0 + (prow >> 2);
    const int kkA1 = 8 * w + 4 + (prow >> 2);

    // ---- phase 1: A0 (4 frags) + A1 tl=0 s=0,1 ----
    stg[tid * 6 + 0] = make_a0(Whh0, kkA0, gate, q, 0);
    stg[tid * 6 + 1] = make_a0(Whh0, kkA0, gate, q, 1);
    stg[tid * 6 + 2] = make_a0(Whh0, kkA1, gate, q, 0);
    stg[tid * 6 + 3] = make_a0(Whh0, kkA1, gate, q, 1);
    stg[tid * 6 + 4] = make_a1(Wih1, Whh1, bih1, bhh1, kkA0, gate, q, 0);
    stg[tid * 6 + 5] = make_a1(Wih1, Whh1, bih1, bhh1, kkA0, gate, q, 1);
    __syncthreads();
    half8 A0[2][2], A1[2][4];
    A0[0][0] = stg[tid * 6 + 0];
    A0[0][1] = stg[tid * 6 + 1];
    A0[1][0] = stg[tid * 6 + 2];
    A0[1][1] = stg[tid * 6 + 3];
    A1[0][0] = stg[tid * 6 + 4];
    A1[0][1] = stg[tid * 6 + 5];
    __syncthreads();
    // ---- phase 2: A1 tl=0 s=2,3 + A1 tl=1 s=0..3 ----
    stg[tid * 6 + 0] = make_a1(Wih1, Whh1, bih1, bhh1, kkA0, gate, q, 2);
    stg[tid * 6 + 1] = make_a1(Wih1, Whh1, bih1, bhh1, kkA0, gate, q, 3);
    stg[tid * 6 + 2] = make_a1(Wih1, Whh1, bih1, bhh1, kkA1, gate, q, 0);
    stg[tid * 6 + 3] = make_a1(Wih1, Whh1, bih1, bhh1, kkA1, gate, q, 1);
    stg[tid * 6 + 4] = make_a1(Wih1, Whh1, bih1, bhh1, kkA1, gate, q, 2);
    stg[tid * 6 + 5] = make_a1(Wih1, Whh1, bih1, bhh1, kkA1, gate, q, 3);
    __syncthreads();
    A1[0][2] = stg[tid * 6 + 0];
    A1[0][3] = stg[tid * 6 + 1];
    A1[1][0] = stg[tid * 6 + 2];
    A1[1][1] = stg[tid * 6 + 3];
    A1[1][2] = stg[tid * 6 + 4];
    A1[1][3] = stg[tid * 6 + 5];
    __syncthreads();

    // ---- overlay B2 + h1f on the (now dead) staging buffer ----
    _Float16 (*B2)[4][4][16][8] = (_Float16 (*)[4][4][16][8])smem;  // 16384B
    float (*h1f)[52] = (float (*)[52])(smem + 16384);               // 416B
    for (int i = tid; i < 8192; i += 512) ((_Float16*)B2)[i] = (_Float16)0.0f;
    __syncthreads();
    if (tid < 4) {   // constant-1.0 bias channel at k=100 (s=3,q=0,j=4), cols 0..1
        B2[tid >> 1][3][0][tid & 1][4] = (_Float16)1.0f;
    }
    float c0[2] = {0.0f, 0.0f}, c1[2] = {0.0f, 0.0f};

    // xp prefetch for t=0 (bias0 already folded in by xproj)
    half4v xc[2], xn[2];
    #pragma unroll
    for (int tl = 0; tl < 2; ++tl) {
        const int kkB = 8 * w + 4 * tl + q;
        half4v z = {(_Float16)0.f, (_Float16)0.f, (_Float16)0.f, (_Float16)0.f};
        xc[tl] = z;
        if (kkB < H && col < 2)
            xc[tl] = *(const half4v*)&XP[((size_t)(b0 + col) * TT + 0) * XPLD + 4 * kkB];
    }
    __syncthreads();

    for (int t = 0; t < TT; ++t) {
        const int rb = t & 1, wb = rb ^ 1;
        // prefetch xp(t+1) first (longest latency; drained by end-of-iter barrier)
        #pragma unroll
        for (int tl = 0; tl < 2; ++tl) {
            const int kkB = 8 * w + 4 * tl + q;
            half4v z = {(_Float16)0.f, (_Float16)0.f, (_Float16)0.f, (_Float16)0.f};
            xn[tl] = z;
            if (t + 1 < TT && kkB < H && col < 2)
                xn[tl] = *(const half4v*)&XP[((size_t)(b0 + col) * TT + (t + 1)) * XPLD + 4 * kkB];
        }
        // B-frag reads: addr = lane*16 -> conflict-free
        half8 bf[4];
        #pragma unroll
        for (int s = 0; s < 4; ++s) bf[s] = *(const half8*)&B2[rb][s][q][col][0];
        // MFMA: gates0(t), gates1(t-1)  (acc1 split into 2 chains)
        floatx4 acc0[2], acc1a[2], acc1b[2];
        #pragma unroll
        for (int tl = 0; tl < 2; ++tl) {
            acc0[tl] = (floatx4)(0.0f); acc1a[tl] = (floatx4)(0.0f); acc1b[tl] = (floatx4)(0.0f);
        }
        #pragma unroll
        for (int tl = 0; tl < 2; ++tl) {
            acc0[tl]  = __builtin_amdgcn_mfma_f32_16x16x32_f16(A0[tl][0], bf[0], acc0[tl], 0, 0, 0);
            acc0[tl]  = __builtin_amdgcn_mfma_f32_16x16x32_f16(A0[tl][1], bf[1], acc0[tl], 0, 0, 0);
            acc1a[tl] = __builtin_amdgcn_mfma_f32_16x16x32_f16(A1[tl][0], bf[0], acc1a[tl], 0, 0, 0);
            acc1a[tl] = __builtin_amdgcn_mfma_f32_16x16x32_f16(A1[tl][1], bf[1], acc1a[tl], 0, 0, 0);
            acc1b[tl] = __builtin_amdgcn_mfma_f32_16x16x32_f16(A1[tl][2], bf[2], acc1b[tl], 0, 0, 0);
            acc1b[tl] = __builtin_amdgcn_mfma_f32_16x16x32_f16(A1[tl][3], bf[3], acc1b[tl], 0, 0, 0);
        }
        // stage B (in-register): L0 -> h0(t); L1 -> h1(t-1), skip at t==0
        #pragma unroll
        for (int tl = 0; tl < 2; ++tl) {
            const int kkB = 8 * w + 4 * tl + q;
            if (kkB < H) {
                {
                    const float gi = sigm(acc0[tl][0] + (float)xc[tl][0]);
                    const float gf = sigm(acc0[tl][1] + (float)xc[tl][1]);
                    const float gg = tanhx(acc0[tl][2] + (float)xc[tl][2]);
                    const float go = sigm(acc0[tl][3] + (float)xc[tl][3]);
                    c0[tl] = gf * c0[tl] + gi * gg;
                    const float hv = go * tanhx(c0[tl]);
                    if (col < 2) B2[wb][kkB >> 5][(kkB >> 3) & 3][col][kkB & 7] = (_Float16)hv;
                }
                if (t > 0) {
                    const float qi = sigm(acc1a[tl][0] + acc1b[tl][0]);
                    const float qf = sigm(acc1a[tl][1] + acc1b[tl][1]);
                    const float qg = tanhx(acc1a[tl][2] + acc1b[tl][2]);
                    const float qo = sigm(acc1a[tl][3] + acc1b[tl][3]);
                    c1[tl] = qf * c1[tl] + qi * qg;
                    const float hv = qo * tanhx(c1[tl]);
                    const int k1 = H + kkB;
                    if (col < 2) B2[wb][k1 >> 5][(k1 >> 3) & 3][col][k1 & 7] = (_Float16)hv;
                }
            }
        }
        xc[0] = xn[0]; xc[1] = xn[1];
        __syncthreads();
    }
    // ---- tail: gates1(TT-1) from buf[TT&1] = [h0(TT-1); h1(TT-2); 1.0] ----
    {
        const int rb = TT & 1;
        half8 bf[4];
        #pragma unroll
        for (int s = 0; s < 4; ++s) bf[s] = *(const half8*)&B2[rb][s][q][col][0];
        #pragma unroll
        for (int tl = 0; tl < 2; ++tl) {
            floatx4 a1 = (floatx4)(0.0f), b1 = (floatx4)(0.0f);
            a1 = __builtin_amdgcn_mfma_f32_16x16x32_f16(A1[tl][0], bf[0], a1, 0, 0, 0);
            a1 = __builtin_amdgcn_mfma_f32_16x16x32_f16(A1[tl][1], bf[1], a1, 0, 0, 0);
            b1 = __builtin_amdgcn_mfma_f32_16x16x32_f16(A1[tl][2], bf[2], b1, 0, 0, 0);
            b1 = __builtin_amdgcn_mfma_f32_16x16x32_f16(A1[tl][3], bf[3], b1, 0, 0, 0);
            const int kkB = 8 * w + 4 * tl + q;
            if (kkB < H && col < 2) {
                const float qi = sigm(a1[0] + b1[0]);
                const float qf = sigm(a1[1] + b1[1]);
                const float qg = tanhx(a1[2] + b1[2]);
                const float qo = sigm(a1[3] + b1[3]);
                c1[tl] = qf * c1[tl] + qi * qg;
                h1f[col][kkB] = qo * tanhx(c1[tl]);
            }
        }
        __syncthreads();
    }
    // ---- fused FC on h1(TT-1): 2 rows x 144 outs ----
    if (tid < 2 * ODIM) {
        const int r = tid / ODIM, o = tid - r * ODIM;
        float s = bfc[o];
        const float* wr = Wfc + (size_t)o * H;
        #pragma unroll
        for (int k = 0; k < H; ++k) s += wr[k] * h1f[r][k];
        out[(size_t)(b0 + r) * ODIM + o] = s;
    }
}

extern "C" void kernel_launch(void* const* d_in, const int* in_sizes, int n_in,
                              void* d_out, int out_size, void* d_ws, size_t ws_size,
                              hipStream_t stream) {
    const float* x    = (const float*)d_in[0];
    const float* wih0 = (const float*)d_in[1];
    const float* whh0 = (const float*)d_in[2];
    const float* bih0 = (const float*)d_in[3];
    const float* bhh0 = (const float*)d_in[4];
    const float* wih1 = (const float*)d_in[5];
    const float* whh1 = (const float*)d_in[6];
    const float* bih1 = (const float*)d_in[7];
    const float* bhh1 = (const float*)d_in[8];
    const float* wfc  = (const float*)d_in[9];
    const float* bfc  = (const float*)d_in[10];
    float* outp = (float*)d_out;

    _Float16* XP = (_Float16*)d_ws;                                       // 54.5 MB
    _Float16* Wf = (_Float16*)((char*)d_ws + (size_t)131072 * XPLD * 2);  // 66.5 KB

    wcvt<<<(XPLD * WKP + 255) / 256, 256, 0, stream>>>(wih0, Wf);
    xproj<<<BATCH * TT / 64, 256, 0, stream>>>(x, Wf, bih0, bhh0, XP);
    lstm_mfma<<<BATCH / 2, 512, 0, stream>>>(XP, whh0, wih1, whh1,
                                             bih1, bhh1, wfc, bfc, outp);
}

// Round 7
// 677.019 us; speedup vs baseline: 1.0037x; 1.0037x over previous
//
#include <hip/hip_runtime.h>
#include <hip/hip_bf16.h>
#include <hip/hip_fp16.h>
#include <cstdint>
#include <cstddef>

#define H    50
#define G4   200      // 4*H gates
#define TT   256      // timesteps
#define BATCH 512
#define KDIM 144      // layer-0 input dim
#define ODIM 144      // FC output dim
#define XPLD 208      // XP row width: gate-interleaved p = kk*4+gate, kk padded to 52
#define WKP  160      // padded K for the xproj weight panel

typedef _Float16 half8  __attribute__((ext_vector_type(8)));
typedef _Float16 half4v __attribute__((ext_vector_type(4)));
typedef float    floatx4 __attribute__((ext_vector_type(4)));

__device__ __forceinline__ float sigm(float x) {
    return 1.0f / (1.0f + __expf(-x));
}
__device__ __forceinline__ float tanhx(float x) {
    float e = __expf(2.0f * x);
    return 1.0f - 2.0f / (e + 1.0f);
}

// ---------- Kernel 0: W_ih0 [200][144] fp32 -> Wf [208][160] f16, rows permuted
// to p = kk*4 + gate (XP columns come out gate-interleaved). ----------
__global__ __launch_bounds__(256) void wcvt(const float* __restrict__ W,
                                            _Float16* __restrict__ Wf) {
    const int idx = blockIdx.x * 256 + threadIdx.x;
    if (idx >= XPLD * WKP) return;
    const int p = idx / WKP, k = idx % WKP;
    const int kk = p >> 2, g = p & 3;
    const float v = (kk < H && k < KDIM) ? W[(size_t)(g * H + kk) * KDIM + k] : 0.0f;
    Wf[idx] = (_Float16)v;
}

// ---------- Kernel 1: XP[m][208] (f16) = X[m][144] @ Wf^T + bias0, MFMA ----------
// 2048 WGs x 256 thr. X tile staged in LDS (coalesced float4 global reads),
// A-frags built from LDS. Output staged in overlaid LDS, written with 16B stores.
__global__ __launch_bounds__(256) void xproj(const float* __restrict__ X,
                                             const _Float16* __restrict__ Wf,
                                             const float* __restrict__ bih0,
                                             const float* __restrict__ bhh0,
                                             _Float16* __restrict__ XP) {
    __shared__ __align__(16) unsigned char sm[64 * 148 * 4];   // 37888 B
    float    (*Xs)[148]  = (float (*)[148])sm;                 // phase 1
    _Float16 (*ost)[216] = (_Float16 (*)[216])sm;              // phase 2 overlay
    const int tid  = threadIdx.x;
    const int lane = tid & 63;
    const int wv   = tid >> 6;
    const int mrow = lane & 15;
    const int q    = lane >> 4;
    const int mb   = blockIdx.x * 64;

    // stage X tile, coalesced: 64 rows x 36 float4
    for (int idx = tid; idx < 64 * 36; idx += 256) {
        const int r = idx / 36, c4 = idx - r * 36;
        *(float4*)&Xs[r][c4 * 4] = *(const float4*)&X[(size_t)(mb + r) * KDIM + c4 * 4];
    }
    // per-lane bias for its 13 C columns (p = n*16 + mrow)
    float bcol[13];
    #pragma unroll
    for (int n = 0; n < 13; ++n) {
        const int p = n * 16 + mrow;
        const int kk = p >> 2, g = p & 3;
        bcol[n] = (kk < H) ? (bih0[g * H + kk] + bhh0[g * H + kk]) : 0.0f;
    }
    __syncthreads();

    floatx4 acc[13];
    #pragma unroll
    for (int n = 0; n < 13; ++n) acc[n] = (floatx4)(0.0f);
    #pragma unroll
    for (int s = 0; s < 5; ++s) {
        const int kbase = s * 32 + q * 8;
        half8 a;
        if (kbase + 7 < KDIM) {
            const float4 x0 = *(const float4*)&Xs[wv * 16 + mrow][kbase];
            const float4 x1 = *(const float4*)&Xs[wv * 16 + mrow][kbase + 4];
            a[0] = (_Float16)x0.x; a[1] = (_Float16)x0.y;
            a[2] = (_Float16)x0.z; a[3] = (_Float16)x0.w;
            a[4] = (_Float16)x1.x; a[5] = (_Float16)x1.y;
            a[6] = (_Float16)x1.z; a[7] = (_Float16)x1.w;
        } else {
            #pragma unroll
            for (int j = 0; j < 8; ++j) a[j] = (_Float16)0.0f;
        }
        #pragma unroll
        for (int n = 0; n < 13; ++n) {
            const half8 b = *(const half8*)&Wf[(size_t)(n * 16 + mrow) * WKP + s * 32 + q * 8];
            acc[n] = __builtin_amdgcn_mfma_f32_16x16x32_f16(a, b, acc[n], 0, 0, 0);
        }
    }
    __syncthreads();   // Xs dead; overlay ost
    // C layout: col p = n*16+mrow, row m = q*4+r -> scatter into LDS (+bias, f32)
    #pragma unroll
    for (int n = 0; n < 13; ++n) {
        #pragma unroll
        for (int r = 0; r < 4; ++r) {
            ost[wv * 16 + q * 4 + r][n * 16 + mrow] = (_Float16)(acc[n][r] + bcol[n]);
        }
    }
    __syncthreads();
    // coalesced write-out: 64 rows x 26 16B-chunks
    for (int c = tid; c < 64 * 26; c += 256) {
        const int m = c / 26, j = c - m * 26;
        const half8 v = *(const half8*)&ost[m][j * 8];
        *(half8*)&XP[(size_t)(mb + m) * XPLD + j * 8] = v;
    }
}

// ---------- helpers to build lstm A-fragments (A: m = lane&15, k = q*8+j) ----------
__device__ __forceinline__ half8 make_a0(const float* __restrict__ Whh0,
                                         int kkA, int gate, int q, int s) {
    const float* r0 = Whh0 + (size_t)(gate * H + (kkA < H ? kkA : 0)) * H;
    half8 r;
    #pragma unroll
    for (int j = 0; j < 8; ++j) {
        const int k = s * 32 + q * 8 + j;
        r[j] = (_Float16)((kkA < H && k < H) ? r0[k] : 0.0f);
    }
    return r;
}
__device__ __forceinline__ half8 make_a1(const float* __restrict__ Wih1,
                                         const float* __restrict__ Whh1,
                                         const float* __restrict__ bih1,
                                         const float* __restrict__ bhh1,
                                         int kkA, int gate, int q, int s) {
    const int p = gate * H + (kkA < H ? kkA : 0);
    half8 r;
    #pragma unroll
    for (int j = 0; j < 8; ++j) {
        const int k = s * 32 + q * 8 + j;
        float v = 0.0f;
        if (kkA < H) {
            if (k < H)            v = Wih1[(size_t)p * H + k];
            else if (k < 2 * H)   v = Whh1[(size_t)p * H + (k - H)];
            else if (k == 100)    v = bih1[p] + bhh1[p];   // bias rides constant-1 B row
        }
        r[j] = (_Float16)v;
    }
    return r;
}

// ---------- Kernel 2: MFMA recurrence, 256 WGs x 512 thr, 2 batch rows/WG ----------
// Row space (512): [0,256) = L0 gates (p = kk*4+gate), [256,512) = L1 gates.
// K pad 128: k 0..49 = h0, 50..99 = h1, k=100 = constant 1.0 (bias1 channel).
// A-frags built once, then PINNED in VGPRs via opaque asm ("+v") so the compiler
// cannot rematerialize them from global (R5/R6 bug: 27GB FETCH/launch).
// B double-buffered in LDS [buf][s][q][col][j]; hot read = lane*16, conflict-free.
// C regs are the 4 gates of one hidden unit -> in-register epilogue, 1 barrier/step.
__global__ __launch_bounds__(512, 1) void lstm_mfma(
    const _Float16* __restrict__ XP,
    const float* __restrict__ Whh0,
    const float* __restrict__ Wih1,
    const float* __restrict__ Whh1,
    const float* __restrict__ bih1, const float* __restrict__ bhh1,
    const float* __restrict__ Wfc,  const float* __restrict__ bfc,
    float* __restrict__ out)
{
    const int b0   = blockIdx.x * 2;
    const int tid  = threadIdx.x;
    const int lane = tid & 63;
    const int w    = tid >> 6;       // wave 0..7
    const int col  = lane & 15;      // B col / C col (batch row for col<2)
    const int q    = lane >> 4;      // 0..3
    const int prow = lane & 15;      // A row within tile
    const int gate = prow & 3;

    __shared__ __align__(16) unsigned char smem[18432];
    _Float16 (*B2)[4][4][16][8] = (_Float16 (*)[4][4][16][8])smem;  // 16384 B
    float (*h1f)[52] = (float (*)[52])(smem + 16384);               // 416 B

    const int kkA0 = 8 * w + 0 + (prow >> 2);
    const int kkA1 = 8 * w + 4 + (prow >> 2);

    // ---- build A-frags from global (once) ----
    half8 A0[2][2], A1[2][4];
    A0[0][0] = make_a0(Whh0, kkA0, gate, q, 0);
    A0[0][1] = make_a0(Whh0, kkA0, gate, q, 1);
    A0[1][0] = make_a0(Whh0, kkA1, gate, q, 0);
    A0[1][1] = make_a0(Whh0, kkA1, gate, q, 1);
    A1[0][0] = make_a1(Wih1, Whh1, bih1, bhh1, kkA0, gate, q, 0);
    A1[0][1] = make_a1(Wih1, Whh1, bih1, bhh1, kkA0, gate, q, 1);
    A1[0][2] = make_a1(Wih1, Whh1, bih1, bhh1, kkA0, gate, q, 2);
    A1[0][3] = make_a1(Wih1, Whh1, bih1, bhh1, kkA0, gate, q, 3);
    A1[1][0] = make_a1(Wih1, Whh1, bih1, bhh1, kkA1, gate, q, 0);
    A1[1][1] = make_a1(Wih1, Whh1, bih1, bhh1, kkA1, gate, q, 1);
    A1[1][2] = make_a1(Wih1, Whh1, bih1, bhh1, kkA1, gate, q, 2);
    A1[1][3] = make_a1(Wih1, Whh1, bih1, bhh1, kkA1, gate, q, 3);
    // ---- PIN: opaque asm marks the frags as asm-modified; the compiler can no
    // longer rematerialize them from the global loads above -> resident in VGPRs.
    asm volatile(""
        : "+v"(A0[0][0]), "+v"(A0[0][1]), "+v"(A0[1][0]), "+v"(A0[1][1]),
          "+v"(A1[0][0]), "+v"(A1[0][1]), "+v"(A1[0][2]), "+v"(A1[0][3]),
          "+v"(A1[1][0]), "+v"(A1[1][1]), "+v"(A1[1][2]), "+v"(A1[1][3]));

    // ---- zero B buffers; set constant-1.0 bias channel at k=100, cols 0..1 ----
    for (int i = tid; i < 8192; i += 512) ((_Float16*)B2)[i] = (_Float16)0.0f;
    __syncthreads();
    if (tid < 4) {   // k=100 -> s=3, q'=0, j=4
        B2[tid >> 1][3][0][tid & 1][4] = (_Float16)1.0f;
    }
    float c0[2] = {0.0f, 0.0f}, c1[2] = {0.0f, 0.0f};

    // xp prefetch for t=0 (bias0 already folded in by xproj)
    half4v xc[2], xn[2];
    #pragma unroll
    for (int tl = 0; tl < 2; ++tl) {
        const int kkB = 8 * w + 4 * tl + q;
        half4v z = {(_Float16)0.f, (_Float16)0.f, (_Float16)0.f, (_Float16)0.f};
        xc[tl] = z;
        if (kkB < H && col < 2)
            xc[tl] = *(const half4v*)&XP[((size_t)(b0 + col) * TT + 0) * XPLD + 4 * kkB];
    }
    __syncthreads();

    for (int t = 0; t < TT; ++t) {
        const int rb = t & 1, wb = rb ^ 1;
        // prefetch xp(t+1) first (longest latency; drained by end-of-iter barrier)
        #pragma unroll
        for (int tl = 0; tl < 2; ++tl) {
            const int kkB = 8 * w + 4 * tl + q;
            half4v z = {(_Float16)0.f, (_Float16)0.f, (_Float16)0.f, (_Float16)0.f};
            xn[tl] = z;
            if (t + 1 < TT && kkB < H && col < 2)
                xn[tl] = *(const half4v*)&XP[((size_t)(b0 + col) * TT + (t + 1)) * XPLD + 4 * kkB];
        }
        // B-frag reads: addr = lane*16 -> conflict-free
        half8 bf[4];
        #pragma unroll
        for (int s = 0; s < 4; ++s) bf[s] = *(const half8*)&B2[rb][s][q][col][0];
        // MFMA: gates0(t), gates1(t-1)  (acc1 split into 2 chains)
        floatx4 acc0[2], acc1a[2], acc1b[2];
        #pragma unroll
        for (int tl = 0; tl < 2; ++tl) {
            acc0[tl] = (floatx4)(0.0f); acc1a[tl] = (floatx4)(0.0f); acc1b[tl] = (floatx4)(0.0f);
        }
        #pragma unroll
        for (int tl = 0; tl < 2; ++tl) {
            acc0[tl]  = __builtin_amdgcn_mfma_f32_16x16x32_f16(A0[tl][0], bf[0], acc0[tl], 0, 0, 0);
            acc0[tl]  = __builtin_amdgcn_mfma_f32_16x16x32_f16(A0[tl][1], bf[1], acc0[tl], 0, 0, 0);
            acc1a[tl] = __builtin_amdgcn_mfma_f32_16x16x32_f16(A1[tl][0], bf[0], acc1a[tl], 0, 0, 0);
            acc1a[tl] = __builtin_amdgcn_mfma_f32_16x16x32_f16(A1[tl][1], bf[1], acc1a[tl], 0, 0, 0);
            acc1b[tl] = __builtin_amdgcn_mfma_f32_16x16x32_f16(A1[tl][2], bf[2], acc1b[tl], 0, 0, 0);
            acc1b[tl] = __builtin_amdgcn_mfma_f32_16x16x32_f16(A1[tl][3], bf[3], acc1b[tl], 0, 0, 0);
        }
        // stage B (in-register): L0 -> h0(t); L1 -> h1(t-1), skip at t==0
        #pragma unroll
        for (int tl = 0; tl < 2; ++tl) {
            const int kkB = 8 * w + 4 * tl + q;
            if (kkB < H) {
                {
                    const float gi = sigm(acc0[tl][0] + (float)xc[tl][0]);
                    const float gf = sigm(acc0[tl][1] + (float)xc[tl][1]);
                    const float gg = tanhx(acc0[tl][2] + (float)xc[tl][2]);
                    const float go = sigm(acc0[tl][3] + (float)xc[tl][3]);
                    c0[tl] = gf * c0[tl] + gi * gg;
                    const float hv = go * tanhx(c0[tl]);
                    if (col < 2) B2[wb][kkB >> 5][(kkB >> 3) & 3][col][kkB & 7] = (_Float16)hv;
                }
                if (t > 0) {
                    const float qi = sigm(acc1a[tl][0] + acc1b[tl][0]);
                    const float qf = sigm(acc1a[tl][1] + acc1b[tl][1]);
                    const float qg = tanhx(acc1a[tl][2] + acc1b[tl][2]);
                    const float qo = sigm(acc1a[tl][3] + acc1b[tl][3]);
                    c1[tl] = qf * c1[tl] + qi * qg;
                    const float hv = qo * tanhx(c1[tl]);
                    const int k1 = H + kkB;
                    if (col < 2) B2[wb][k1 >> 5][(k1 >> 3) & 3][col][k1 & 7] = (_Float16)hv;
                }
            }
        }
        xc[0] = xn[0]; xc[1] = xn[1];
        __syncthreads();
    }
    // ---- tail: gates1(TT-1) from buf[TT&1] = [h0(TT-1); h1(TT-2); 1.0] ----
    {
        const int rb = TT & 1;
        half8 bf[4];
        #pragma unroll
        for (int s = 0; s < 4; ++s) bf[s] = *(const half8*)&B2[rb][s][q][col][0];
        #pragma unroll
        for (int tl = 0; tl < 2; ++tl) {
            floatx4 a1 = (floatx4)(0.0f), b1 = (floatx4)(0.0f);
            a1 = __builtin_amdgcn_mfma_f32_16x16x32_f16(A1[tl][0], bf[0], a1, 0, 0, 0);
            a1 = __builtin_amdgcn_mfma_f32_16x16x32_f16(A1[tl][1], bf[1], a1, 0, 0, 0);
            b1 = __builtin_amdgcn_mfma_f32_16x16x32_f16(A1[tl][2], bf[2], b1, 0, 0, 0);
            b1 = __builtin_amdgcn_mfma_f32_16x16x32_f16(A1[tl][3], bf[3], b1, 0, 0, 0);
            const int kkB = 8 * w + 4 * tl + q;
            if (kkB < H && col < 2) {
                const float qi = sigm(a1[0] + b1[0]);
                const float qf = sigm(a1[1] + b1[1]);
                const float qg = tanhx(a1[2] + b1[2]);
                const float qo = sigm(a1[3] + b1[3]);
                c1[tl] = qf * c1[tl] + qi * qg;
                h1f[col][kkB] = qo * tanhx(c1[tl]);
            }
        }
        __syncthreads();
    }
    // ---- fused FC on h1(TT-1): 2 rows x 144 outs ----
    if (tid < 2 * ODIM) {
        const int r = tid / ODIM, o = tid - r * ODIM;
        float s = bfc[o];
        const float* wr = Wfc + (size_t)o * H;
        #pragma unroll
        for (int k = 0; k < H; ++k) s += wr[k] * h1f[r][k];
        out[(size_t)(b0 + r) * ODIM + o] = s;
    }
}

extern "C" void kernel_launch(void* const* d_in, const int* in_sizes, int n_in,
                              void* d_out, int out_size, void* d_ws, size_t ws_size,
                              hipStream_t stream) {
    const float* x    = (const float*)d_in[0];
    const float* wih0 = (const float*)d_in[1];
    const float* whh0 = (const float*)d_in[2];
    const float* bih0 = (const float*)d_in[3];
    const float* bhh0 = (const float*)d_in[4];
    const float* wih1 = (const float*)d_in[5];
    const float* whh1 = (const float*)d_in[6];
    const float* bih1 = (const float*)d_in[7];
    const float* bhh1 = (const float*)d_in[8];
    const float* wfc  = (const float*)d_in[9];
    const float* bfc  = (const float*)d_in[10];
    float* outp = (float*)d_out;

    _Float16* XP = (_Float16*)d_ws;                                       // 54.5 MB
    _Float16* Wf = (_Float16*)((char*)d_ws + (size_t)131072 * XPLD * 2);  // 66.5 KB

    wcvt<<<(XPLD * WKP + 255) / 256, 256, 0, stream>>>(wih0, Wf);
    xproj<<<BATCH * TT / 64, 256, 0, stream>>>(x, Wf, bih0, bhh0, XP);
    lstm_mfma<<<BATCH / 2, 512, 0, stream>>>(XP, whh0, wih1, whh1,
                                             bih1, bhh1, wfc, bfc, outp);
}

// Round 8
// 624.118 us; speedup vs baseline: 1.0888x; 1.0848x over previous
//
#include <hip/hip_runtime.h>
#include <hip/hip_fp16.h>
#include <cstdint>
#include <cstddef>

#define H    50
#define G4   200      // 4*H gates
#define TT   256      // timesteps
#define BATCH 512
#define KDIM 144      // layer-0 input dim
#define ODIM 144      // FC output dim
#define XPLD 208      // XP row width: gate-interleaved p = kk*4+gate, kk padded to 52
#define WKP  160      // padded K for the xproj weight panel

typedef _Float16 half8  __attribute__((ext_vector_type(8)));
typedef _Float16 half4v __attribute__((ext_vector_type(4)));
typedef float    floatx4 __attribute__((ext_vector_type(4)));
typedef int      int4v  __attribute__((ext_vector_type(4)));

__device__ __forceinline__ float sigm(float x) {
    return 1.0f / (1.0f + __expf(-x));
}
__device__ __forceinline__ float tanhx(float x) {
    float e = __expf(2.0f * x);
    return 1.0f - 2.0f / (e + 1.0f);
}

// ---------- Kernel 0a: W_ih0 [200][144] fp32 -> Wf [208][160] f16, rows permuted
// to p = kk*4 + gate (XP columns come out gate-interleaved). ----------
__global__ __launch_bounds__(256) void wcvt(const float* __restrict__ W,
                                            _Float16* __restrict__ Wf) {
    const int idx = blockIdx.x * 256 + threadIdx.x;
    if (idx >= XPLD * WKP) return;
    const int p = idx / WKP, k = idx % WKP;
    const int kk = p >> 2, g = p & 3;
    const float v = (kk < H && k < KDIM) ? W[(size_t)(g * H + kk) * KDIM + k] : 0.0f;
    Wf[idx] = (_Float16)v;
}

// ---------- helpers to build lstm A-fragments (A: m = lane&15, k = q*8+j) ----------
__device__ __forceinline__ half8 make_a0(const float* __restrict__ Whh0,
                                         int kkA, int gate, int q, int s) {
    const float* r0 = Whh0 + (size_t)(gate * H + (kkA < H ? kkA : 0)) * H;
    half8 r;
    #pragma unroll
    for (int j = 0; j < 8; ++j) {
        const int k = s * 32 + q * 8 + j;
        r[j] = (_Float16)((kkA < H && k < H) ? r0[k] : 0.0f);
    }
    return r;
}
__device__ __forceinline__ half8 make_a1(const float* __restrict__ Wih1,
                                         const float* __restrict__ Whh1,
                                         const float* __restrict__ bih1,
                                         const float* __restrict__ bhh1,
                                         int kkA, int gate, int q, int s) {
    const int p = gate * H + (kkA < H ? kkA : 0);
    half8 r;
    #pragma unroll
    for (int j = 0; j < 8; ++j) {
        const int k = s * 32 + q * 8 + j;
        float v = 0.0f;
        if (kkA < H) {
            if (k < H)            v = Wih1[(size_t)p * H + k];
            else if (k < 2 * H)   v = Whh1[(size_t)p * H + (k - H)];
            else if (k == 100)    v = bih1[p] + bhh1[p];   // bias rides constant-1 B row
        }
        r[j] = (_Float16)v;
    }
    return r;
}

// ---------- Kernel 0b: pre-bake the 12 recurrence A-fragments per lstm thread ----
// Acat[tid][12][8] f16 (98,304 B). Same (w,lane)->frag mapping as lstm_mfma, so
// lstm's load is 12 contiguous dwordx4 per thread (L2-resident for every WG).
__global__ __launch_bounds__(512) void wprep(const float* __restrict__ Whh0,
                                             const float* __restrict__ Wih1,
                                             const float* __restrict__ Whh1,
                                             const float* __restrict__ bih1,
                                             const float* __restrict__ bhh1,
                                             _Float16* __restrict__ Acat) {
    const int tid  = threadIdx.x;
    const int lane = tid & 63;
    const int w    = tid >> 6;
    const int prow = lane & 15;
    const int q    = lane >> 4;
    const int gate = prow & 3;
    const int kkA0 = 8 * w + 0 + (prow >> 2);
    const int kkA1 = 8 * w + 4 + (prow >> 2);
    half8* dst = (half8*)(Acat + (size_t)tid * 96);
    dst[0] = make_a0(Whh0, kkA0, gate, q, 0);
    dst[1] = make_a0(Whh0, kkA0, gate, q, 1);
    dst[2] = make_a0(Whh0, kkA1, gate, q, 0);
    dst[3] = make_a0(Whh0, kkA1, gate, q, 1);
    #pragma unroll
    for (int s = 0; s < 4; ++s) dst[4 + s] = make_a1(Wih1, Whh1, bih1, bhh1, kkA0, gate, q, s);
    #pragma unroll
    for (int s = 0; s < 4; ++s) dst[8 + s] = make_a1(Wih1, Whh1, bih1, bhh1, kkA1, gate, q, s);
}

// ---------- Kernel 1: XP[m][208] (f16) = X[m][144] @ Wf^T, MFMA ----------
// 2048 WGs x 256 thr. X staged in LDS as f16 (coalesced loads, 19.5KB), output
// staged in overlaid LDS (27.6KB max) -> 2-3 WGs/CU. No bias here (moved to lstm).
__global__ __launch_bounds__(256) void xproj(const float* __restrict__ X,
                                             const _Float16* __restrict__ Wf,
                                             _Float16* __restrict__ XP) {
    __shared__ __align__(16) unsigned char sm[64 * 216 * 2];   // 27648 B
    _Float16 (*Xs)[152]  = (_Float16 (*)[152])sm;              // phase 1 (19456 B)
    _Float16 (*ost)[216] = (_Float16 (*)[216])sm;              // phase 2 overlay
    const int tid  = threadIdx.x;
    const int lane = tid & 63;
    const int wv   = tid >> 6;
    const int mrow = lane & 15;
    const int q    = lane >> 4;
    const int mb   = blockIdx.x * 64;

    // stage X tile as f16, coalesced: 64 rows x 36 half4 chunks
    for (int idx = tid; idx < 64 * 36; idx += 256) {
        const int r = idx / 36, c4 = idx - r * 36;
        const float4 v = *(const float4*)&X[(size_t)(mb + r) * KDIM + c4 * 4];
        half4v h;
        h[0] = (_Float16)v.x; h[1] = (_Float16)v.y;
        h[2] = (_Float16)v.z; h[3] = (_Float16)v.w;
        *(half4v*)&Xs[r][c4 * 4] = h;
    }
    __syncthreads();

    floatx4 acc[13];
    #pragma unroll
    for (int n = 0; n < 13; ++n) acc[n] = (floatx4)(0.0f);
    #pragma unroll
    for (int s = 0; s < 5; ++s) {
        const int kbase = s * 32 + q * 8;
        half8 a;
        if (kbase + 7 < KDIM) {
            a = *(const half8*)&Xs[wv * 16 + mrow][kbase];
        } else {
            #pragma unroll
            for (int j = 0; j < 8; ++j) a[j] = (_Float16)0.0f;
        }
        #pragma unroll
        for (int n = 0; n < 13; ++n) {
            const half8 b = *(const half8*)&Wf[(size_t)(n * 16 + mrow) * WKP + s * 32 + q * 8];
            acc[n] = __builtin_amdgcn_mfma_f32_16x16x32_f16(a, b, acc[n], 0, 0, 0);
        }
    }
    __syncthreads();   // Xs dead; overlay ost
    // C layout: col p = n*16+mrow, row m = q*4+r -> scatter into LDS
    #pragma unroll
    for (int n = 0; n < 13; ++n) {
        #pragma unroll
        for (int r = 0; r < 4; ++r) {
            ost[wv * 16 + q * 4 + r][n * 16 + mrow] = (_Float16)acc[n][r];
        }
    }
    __syncthreads();
    // coalesced write-out: 64 rows x 26 16B-chunks
    for (int c = tid; c < 64 * 26; c += 256) {
        const int m = c / 26, j = c - m * 26;
        const half8 v = *(const half8*)&ost[m][j * 8];
        *(half8*)&XP[(size_t)(mb + m) * XPLD + j * 8] = v;
    }
}

// ---------- Kernel 2: MFMA recurrence, 256 WGs x 512 thr, 2 batch rows/WG ----------
// Row space (512): [0,256) = L0 gates (p = kk*4+gate), [256,512) = L1 gates.
// K pad 128: k 0..49 = h0, 50..99 = h1, k=100 = constant 1.0 (bias1 channel).
// A-frags loaded from pre-baked Acat (12 contiguous dwordx4/thread, L2-resident)
// and pinned into AGPRs via "+a" asm, re-pinned EVERY iteration: asm-defined
// values cannot be rematerialized, and gfx950 MFMA reads A directly from AGPRs.
// B double-buffered in LDS; hot read = lane*16, conflict-free. C regs are the 4
// gates of one hidden unit -> in-register epilogue, 1 barrier/step.
__global__ __launch_bounds__(512, 1) void lstm_mfma(
    const _Float16* __restrict__ XP,
    const _Float16* __restrict__ Acat,
    const float* __restrict__ bih0, const float* __restrict__ bhh0,
    const float* __restrict__ Wfc,  const float* __restrict__ bfc,
    float* __restrict__ out)
{
    const int b0   = blockIdx.x * 2;
    const int tid  = threadIdx.x;
    const int lane = tid & 63;
    const int w    = tid >> 6;       // wave 0..7
    const int col  = lane & 15;      // B col / C col (batch row for col<2)
    const int q    = lane >> 4;      // 0..3

    __shared__ __align__(16) unsigned char smem[18432];
    _Float16 (*B2)[4][4][16][8] = (_Float16 (*)[4][4][16][8])smem;  // 16384 B
    float (*h1f)[52] = (float (*)[52])(smem + 16384);               // 416 B

    // ---- load the 12 pre-baked A-frags; pin into AGPRs ----
    // Ap[0..3] = A0[tl][s] (tl*2+s); Ap[4..11] = A1[tl][s] (4+tl*4+s)
    int4v Ap[12];
    #pragma unroll
    for (int i = 0; i < 12; ++i)
        Ap[i] = __builtin_bit_cast(int4v, *(const half8*)&Acat[(size_t)tid * 96 + i * 8]);
    #pragma unroll
    for (int i = 0; i < 12; ++i) asm volatile("" : "+a"(Ap[i]));

    // ---- per-lane bias0 (moved out of xproj): gates of unit kkB ----
    float4 bs0[2];
    #pragma unroll
    for (int tl = 0; tl < 2; ++tl) {
        const int kkB = 8 * w + 4 * tl + q;
        const int kc  = (kkB < H) ? kkB : 0;
        bs0[tl] = make_float4(bih0[kc] + bhh0[kc],
                              bih0[H + kc] + bhh0[H + kc],
                              bih0[2 * H + kc] + bhh0[2 * H + kc],
                              bih0[3 * H + kc] + bhh0[3 * H + kc]);
    }

    // ---- zero B buffers; set constant-1.0 bias channel at k=100, cols 0..1 ----
    for (int i = tid; i < 8192; i += 512) ((_Float16*)B2)[i] = (_Float16)0.0f;
    __syncthreads();
    if (tid < 4) {   // k=100 -> s=3, q'=0, j=4
        B2[tid >> 1][3][0][tid & 1][4] = (_Float16)1.0f;
    }
    float c0[2] = {0.0f, 0.0f}, c1[2] = {0.0f, 0.0f};

    // xp prefetch for t=0
    half4v xc[2], xn[2];
    #pragma unroll
    for (int tl = 0; tl < 2; ++tl) {
        const int kkB = 8 * w + 4 * tl + q;
        half4v z = {(_Float16)0.f, (_Float16)0.f, (_Float16)0.f, (_Float16)0.f};
        xc[tl] = z;
        if (kkB < H && col < 2)
            xc[tl] = *(const half4v*)&XP[((size_t)(b0 + col) * TT + 0) * XPLD + 4 * kkB];
    }
    __syncthreads();

    for (int t = 0; t < TT; ++t) {
        // re-pin every iteration: forces AGPR residency, blocks remat/sink
        #pragma unroll
        for (int i = 0; i < 12; ++i) asm volatile("" : "+a"(Ap[i]));
        const int rb = t & 1, wb = rb ^ 1;
        // prefetch xp(t+1) (consumed next iteration -> full step to cover latency)
        #pragma unroll
        for (int tl = 0; tl < 2; ++tl) {
            const int kkB = 8 * w + 4 * tl + q;
            half4v z = {(_Float16)0.f, (_Float16)0.f, (_Float16)0.f, (_Float16)0.f};
            xn[tl] = z;
            if (t + 1 < TT && kkB < H && col < 2)
                xn[tl] = *(const half4v*)&XP[((size_t)(b0 + col) * TT + (t + 1)) * XPLD + 4 * kkB];
        }
        // B-frag reads: addr = lane*16 -> conflict-free
        half8 bf[4];
        #pragma unroll
        for (int s = 0; s < 4; ++s) bf[s] = *(const half8*)&B2[rb][s][q][col][0];
        // MFMA: gates0(t), gates1(t-1)  (acc1 split into 2 chains)
        floatx4 acc0[2], acc1a[2], acc1b[2];
        #pragma unroll
        for (int tl = 0; tl < 2; ++tl) {
            acc0[tl] = (floatx4)(0.0f); acc1a[tl] = (floatx4)(0.0f); acc1b[tl] = (floatx4)(0.0f);
        }
        #pragma unroll
        for (int tl = 0; tl < 2; ++tl) {
            acc0[tl]  = __builtin_amdgcn_mfma_f32_16x16x32_f16(__builtin_bit_cast(half8, Ap[tl*2+0]), bf[0], acc0[tl], 0, 0, 0);
            acc0[tl]  = __builtin_amdgcn_mfma_f32_16x16x32_f16(__builtin_bit_cast(half8, Ap[tl*2+1]), bf[1], acc0[tl], 0, 0, 0);
            acc1a[tl] = __builtin_amdgcn_mfma_f32_16x16x32_f16(__builtin_bit_cast(half8, Ap[4+tl*4+0]), bf[0], acc1a[tl], 0, 0, 0);
            acc1a[tl] = __builtin_amdgcn_mfma_f32_16x16x32_f16(__builtin_bit_cast(half8, Ap[4+tl*4+1]), bf[1], acc1a[tl], 0, 0, 0);
            acc1b[tl] = __builtin_amdgcn_mfma_f32_16x16x32_f16(__builtin_bit_cast(half8, Ap[4+tl*4+2]), bf[2], acc1b[tl], 0, 0, 0);
            acc1b[tl] = __builtin_amdgcn_mfma_f32_16x16x32_f16(__builtin_bit_cast(half8, Ap[4+tl*4+3]), bf[3], acc1b[tl], 0, 0, 0);
        }
        // stage B (in-register): L0 -> h0(t); L1 -> h1(t-1), skip at t==0
        #pragma unroll
        for (int tl = 0; tl < 2; ++tl) {
            const int kkB = 8 * w + 4 * tl + q;
            if (kkB < H) {
                {
                    const float gi = sigm(acc0[tl][0] + bs0[tl].x + (float)xc[tl][0]);
                    const float gf = sigm(acc0[tl][1] + bs0[tl].y + (float)xc[tl][1]);
                    const float gg = tanhx(acc0[tl][2] + bs0[tl].z + (float)xc[tl][2]);
                    const float go = sigm(acc0[tl][3] + bs0[tl].w + (float)xc[tl][3]);
                    c0[tl] = gf * c0[tl] + gi * gg;
                    const float hv = go * tanhx(c0[tl]);
                    if (col < 2) B2[wb][kkB >> 5][(kkB >> 3) & 3][col][kkB & 7] = (_Float16)hv;
                }
                if (t > 0) {
                    const float qi = sigm(acc1a[tl][0] + acc1b[tl][0]);
                    const float qf = sigm(acc1a[tl][1] + acc1b[tl][1]);
                    const float qg = tanhx(acc1a[tl][2] + acc1b[tl][2]);
                    const float qo = sigm(acc1a[tl][3] + acc1b[tl][3]);
                    c1[tl] = qf * c1[tl] + qi * qg;
                    const float hv = qo * tanhx(c1[tl]);
                    const int k1 = H + kkB;
                    if (col < 2) B2[wb][k1 >> 5][(k1 >> 3) & 3][col][k1 & 7] = (_Float16)hv;
                }
            }
        }
        xc[0] = xn[0]; xc[1] = xn[1];
        __syncthreads();
    }
    // ---- tail: gates1(TT-1) from buf[TT&1] = [h0(TT-1); h1(TT-2); 1.0] ----
    {
        const int rb = TT & 1;
        half8 bf[4];
        #pragma unroll
        for (int s = 0; s < 4; ++s) bf[s] = *(const half8*)&B2[rb][s][q][col][0];
        #pragma unroll
        for (int tl = 0; tl < 2; ++tl) {
            floatx4 a1 = (floatx4)(0.0f), b1 = (floatx4)(0.0f);
            a1 = __builtin_amdgcn_mfma_f32_16x16x32_f16(__builtin_bit_cast(half8, Ap[4+tl*4+0]), bf[0], a1, 0, 0, 0);
            a1 = __builtin_amdgcn_mfma_f32_16x16x32_f16(__builtin_bit_cast(half8, Ap[4+tl*4+1]), bf[1], a1, 0, 0, 0);
            b1 = __builtin_amdgcn_mfma_f32_16x16x32_f16(__builtin_bit_cast(half8, Ap[4+tl*4+2]), bf[2], b1, 0, 0, 0);
            b1 = __builtin_amdgcn_mfma_f32_16x16x32_f16(__builtin_bit_cast(half8, Ap[4+tl*4+3]), bf[3], b1, 0, 0, 0);
            const int kkB = 8 * w + 4 * tl + q;
            if (kkB < H && col < 2) {
                const float qi = sigm(a1[0] + b1[0]);
                const float qf = sigm(a1[1] + b1[1]);
                const float qg = tanhx(a1[2] + b1[2]);
                const float qo = sigm(a1[3] + b1[3]);
                c1[tl] = qf * c1[tl] + qi * qg;
                h1f[col][kkB] = qo * tanhx(c1[tl]);
            }
        }
        __syncthreads();
    }
    // ---- fused FC on h1(TT-1): 2 rows x 144 outs ----
    if (tid < 2 * ODIM) {
        const int r = tid / ODIM, o = tid - r * ODIM;
        float s = bfc[o];
        const float* wr = Wfc + (size_t)o * H;
        #pragma unroll
        for (int k = 0; k < H; ++k) s += wr[k] * h1f[r][k];
        out[(size_t)(b0 + r) * ODIM + o] = s;
    }
}

extern "C" void kernel_launch(void* const* d_in, const int* in_sizes, int n_in,
                              void* d_out, int out_size, void* d_ws, size_t ws_size,
                              hipStream_t stream) {
    const float* x    = (const float*)d_in[0];
    const float* wih0 = (const float*)d_in[1];
    const float* whh0 = (const float*)d_in[2];
    const float* bih0 = (const float*)d_in[3];
    const float* bhh0 = (const float*)d_in[4];
    const float* wih1 = (const float*)d_in[5];
    const float* whh1 = (const float*)d_in[6];
    const float* bih1 = (const float*)d_in[7];
    const float* bhh1 = (const float*)d_in[8];
    const float* wfc  = (const float*)d_in[9];
    const float* bfc  = (const float*)d_in[10];
    float* outp = (float*)d_out;

    _Float16* XP   = (_Float16*)d_ws;                                       // 54.5 MB
    _Float16* Wf   = (_Float16*)((char*)d_ws + (size_t)131072 * XPLD * 2);  // 66.5 KB
    _Float16* Acat = (_Float16*)((char*)d_ws + (size_t)131072 * XPLD * 2 + XPLD * WKP * 2); // 98.3 KB

    wcvt<<<(XPLD * WKP + 255) / 256, 256, 0, stream>>>(wih0, Wf);
    wprep<<<1, 512, 0, stream>>>(whh0, wih1, whh1, bih1, bhh1, Acat);
    xproj<<<BATCH * TT / 64, 256, 0, stream>>>(x, Wf, XP);
    lstm_mfma<<<BATCH / 2, 512, 0, stream>>>(XP, Acat, bih0, bhh0, wfc, bfc, outp);
}

// Round 9
// 380.687 us; speedup vs baseline: 1.7850x; 1.6394x over previous
//
#include <hip/hip_runtime.h>
#include <hip/hip_fp16.h>
#include <cstdint>
#include <cstddef>

#define H    50
#define TT   256      // timesteps
#define BATCH 512
#define KDIM 144      // layer-0 input dim
#define ODIM 144      // FC output dim

typedef _Float16 half8  __attribute__((ext_vector_type(8)));
typedef _Float16 half4v __attribute__((ext_vector_type(4)));
typedef float    floatx4 __attribute__((ext_vector_type(4)));
typedef int      int4v  __attribute__((ext_vector_type(4)));

__device__ __forceinline__ float rcpf(float x) { return __builtin_amdgcn_rcpf(x); }
__device__ __forceinline__ float sigm(float x) { return rcpf(1.0f + __expf(-x)); }
__device__ __forceinline__ float tanhx(float x) {
    return 1.0f - 2.0f * rcpf(__expf(2.0f * x) + 1.0f);
}

// ---------- A-fragment builders (A layout: row m = lane&15, k = q*8 + j) ----------
// Row space p = kk*4 + gate (gates of one unit land in one lane's 4 C-regs).
__device__ __forceinline__ half8 make_a0(const float* __restrict__ Whh0,
                                         int kkA, int gate, int q, int s) {
    const float* r0 = Whh0 + (size_t)(gate * H + (kkA < H ? kkA : 0)) * H;
    half8 r;
    #pragma unroll
    for (int j = 0; j < 8; ++j) {
        const int k = s * 32 + q * 8 + j;
        r[j] = (_Float16)((kkA < H && k < H) ? r0[k] : 0.0f);
    }
    return r;
}
// x-projection rows: K=160 pad; k<144 = W_ih0, k==144 = bias0 (rides 1.0 B-channel)
__device__ __forceinline__ half8 make_ax(const float* __restrict__ Wih0,
                                         const float* __restrict__ bih0,
                                         const float* __restrict__ bhh0,
                                         int kkA, int gate, int q, int s) {
    const int p = gate * H + (kkA < H ? kkA : 0);
    half8 r;
    #pragma unroll
    for (int j = 0; j < 8; ++j) {
        const int k = s * 32 + q * 8 + j;
        float v = 0.0f;
        if (kkA < H) {
            if (k < KDIM)        v = Wih0[(size_t)p * KDIM + k];
            else if (k == KDIM)  v = bih0[p] + bhh0[p];
        }
        r[j] = (_Float16)v;
    }
    return r;
}
// layer-1 rows: K=128 pad; k<50 = W_ih1 (over h0), 50..99 = W_hh1 (over h1), k==100 = bias1
__device__ __forceinline__ half8 make_a1(const float* __restrict__ Wih1,
                                         const float* __restrict__ Whh1,
                                         const float* __restrict__ bih1,
                                         const float* __restrict__ bhh1,
                                         int kkA, int gate, int q, int s) {
    const int p = gate * H + (kkA < H ? kkA : 0);
    half8 r;
    #pragma unroll
    for (int j = 0; j < 8; ++j) {
        const int k = s * 32 + q * 8 + j;
        float v = 0.0f;
        if (kkA < H) {
            if (k < H)            v = Wih1[(size_t)p * H + k];
            else if (k < 2 * H)   v = Whh1[(size_t)p * H + (k - H)];
            else if (k == 100)    v = bih1[p] + bhh1[p];
        }
        r[j] = (_Float16)v;
    }
    return r;
}

// ---------- Kernel 0: pre-bake the 22 A-fragments per lstm thread ----------
// Acat[tid][22][8] f16 (180 KB, L2-resident). Order:
//   [0..3]  A0  (tl*2+s, s<2)     W_hh0
//   [4..13] Ax  (4+tl*5+s, s<5)   W_ih0 + bias0@k=144
//   [14..21]A1  (14+tl*4+s, s<4)  [W_ih1|W_hh1] + bias1@k=100
__global__ __launch_bounds__(512) void wprep(const float* __restrict__ Whh0,
                                             const float* __restrict__ Wih0,
                                             const float* __restrict__ bih0,
                                             const float* __restrict__ bhh0,
                                             const float* __restrict__ Wih1,
                                             const float* __restrict__ Whh1,
                                             const float* __restrict__ bih1,
                                             const float* __restrict__ bhh1,
                                             _Float16* __restrict__ Acat) {
    const int tid  = threadIdx.x;
    const int lane = tid & 63;
    const int w    = tid >> 6;
    const int prow = lane & 15;
    const int q    = lane >> 4;
    const int gate = prow & 3;
    const int kkA0 = 8 * w + 0 + (prow >> 2);
    const int kkA1 = 8 * w + 4 + (prow >> 2);
    half8* dst = (half8*)(Acat + (size_t)tid * 176);
    dst[0] = make_a0(Whh0, kkA0, gate, q, 0);
    dst[1] = make_a0(Whh0, kkA0, gate, q, 1);
    dst[2] = make_a0(Whh0, kkA1, gate, q, 0);
    dst[3] = make_a0(Whh0, kkA1, gate, q, 1);
    #pragma unroll
    for (int s = 0; s < 5; ++s) dst[4 + s] = make_ax(Wih0, bih0, bhh0, kkA0, gate, q, s);
    #pragma unroll
    for (int s = 0; s < 5; ++s) dst[9 + s] = make_ax(Wih0, bih0, bhh0, kkA1, gate, q, s);
    #pragma unroll
    for (int s = 0; s < 4; ++s) dst[14 + s] = make_a1(Wih1, Whh1, bih1, bhh1, kkA0, gate, q, s);
    #pragma unroll
    for (int s = 0; s < 4; ++s) dst[18 + s] = make_a1(Wih1, Whh1, bih1, bhh1, kkA1, gate, q, s);
}

// ---------- Kernel 1: fully-fused 2-layer LSTM + FC. 256 WGs x 512 thr ----------
// Per step one MFMA pass computes gates0(t) = Whh0·h0(t-1) + Wih0·x(t) + b0 and
// gates1(t-1) = [Wih1|Whh1]·[h0;h1] + b1 (layer-1 lags one step). A-frags pinned
// in AGPRs (R8-proven). col<2 lanes scatter gate-quads to gcat (LDS); 200 threads
// each apply ONE activation set (no 10x redundancy), update c in-register, write
// h (f16) into the double-buffered B2. Waves 4-7 prefetch+stage x(t+1) into XS.
__global__ __launch_bounds__(512, 1) void lstm_fused(
    const float* __restrict__ X,
    const _Float16* __restrict__ Acat,
    const float* __restrict__ Wfc, const float* __restrict__ bfc,
    float* __restrict__ out)
{
    const int b0   = blockIdx.x * 2;
    const int tid  = threadIdx.x;
    const int lane = tid & 63;
    const int w    = tid >> 6;       // wave 0..7
    const int col  = lane & 15;      // B col / C col (batch row for col<2)
    const int q    = lane >> 4;      // 0..3

    __shared__ __align__(16) _Float16 B2[2][4][4][16][8];  // h-state [buf][s][q][col][j]
    __shared__ __align__(16) float    gcat[2][2][64][4];   // [layer][row][unit][gate]
    __shared__ __align__(16) _Float16 XS[2][2][160];       // x(t) [buf][row][k], 1.0@144
    __shared__ float h1f[2][52];

    // ---- load + pin the 22 pre-baked A-frags into AGPRs ----
    int4v Ap[22];
    #pragma unroll
    for (int i = 0; i < 22; ++i)
        Ap[i] = __builtin_bit_cast(int4v, *(const half8*)&Acat[(size_t)tid * 176 + i * 8]);
    #pragma unroll
    for (int i = 0; i < 22; ++i) asm volatile("" : "+a"(Ap[i]));

    // ---- role decode ----
    const bool sb  = tid < 200;              // activation set-thread
    const int  L   = tid / 100;              // layer
    const int  rr2 = (tid % 100) / 50;       // batch row within pair
    const int  kst = tid % 50;               // hidden unit
    float c = 0.0f;

    const int  st     = tid - 256;           // x-stage thread (waves 4-7)
    const bool xs_act = (st >= 0 && st < 72);
    const int  xrow   = xs_act ? st / 36 : 0;
    const int  xc4    = xs_act ? st % 36 : 0;
    const float* xbase = X + ((size_t)(b0 + xrow) * TT) * KDIM + xc4 * 4;

    // ---- init: zero B2, set bias-1.0 channels, stage x(0) ----
    for (int i = tid; i < 4096; i += 512) ((int*)B2)[i] = 0;
    __syncthreads();
    if (tid < 4) {
        B2[tid >> 1][3][0][tid & 1][4] = (_Float16)1.0f;   // k=100 bias1 channel
        XS[tid >> 1][tid & 1][144]     = (_Float16)1.0f;   // k=144 bias0 channel
    }
    if (xs_act) {
        const float4 v = *(const float4*)&xbase[0];
        half4v h;
        h[0] = (_Float16)v.x; h[1] = (_Float16)v.y;
        h[2] = (_Float16)v.z; h[3] = (_Float16)v.w;
        *(half4v*)&XS[0][xrow][xc4 * 4] = h;
    }
    __syncthreads();

    for (int t = 0; t < TT; ++t) {
        #pragma unroll
        for (int i = 0; i < 22; ++i) asm volatile("" : "+a"(Ap[i]));
        const int rb = t & 1, wb = rb ^ 1;
        // phase 1: global prefetch x(t+1) (waves 4-7)
        float4 xl = make_float4(0.f, 0.f, 0.f, 0.f);
        if (xs_act && t + 1 < TT)
            xl = *(const float4*)&xbase[(size_t)(t + 1) * KDIM];
        // phase 2: LDS fragment reads (conflict-free / broadcast) + MFMA
        half8 bf[4];
        #pragma unroll
        for (int s = 0; s < 4; ++s) bf[s] = *(const half8*)&B2[rb][s][q][col][0];
        half8 xf[5];
        #pragma unroll
        for (int s = 0; s < 5; ++s) xf[s] = *(const half8*)&XS[rb][col & 1][s * 32 + q * 8];
        floatx4 a0[2], a1[2];
        #pragma unroll
        for (int tl = 0; tl < 2; ++tl) { a0[tl] = (floatx4)(0.0f); a1[tl] = (floatx4)(0.0f); }
        #pragma unroll
        for (int tl = 0; tl < 2; ++tl) {
            a0[tl] = __builtin_amdgcn_mfma_f32_16x16x32_f16(__builtin_bit_cast(half8, Ap[tl*2+0]), bf[0], a0[tl], 0, 0, 0);
            a0[tl] = __builtin_amdgcn_mfma_f32_16x16x32_f16(__builtin_bit_cast(half8, Ap[tl*2+1]), bf[1], a0[tl], 0, 0, 0);
            #pragma unroll
            for (int s = 0; s < 5; ++s)
                a0[tl] = __builtin_amdgcn_mfma_f32_16x16x32_f16(__builtin_bit_cast(half8, Ap[4+tl*5+s]), xf[s], a0[tl], 0, 0, 0);
            #pragma unroll
            for (int s = 0; s < 4; ++s)
                a1[tl] = __builtin_amdgcn_mfma_f32_16x16x32_f16(__builtin_bit_cast(half8, Ap[14+tl*4+s]), bf[s], a1[tl], 0, 0, 0);
        }
        // phase 3: scatter gate-quads of the 2 real batch rows
        if (col < 2) {
            #pragma unroll
            for (int tl = 0; tl < 2; ++tl) {
                *(floatx4*)&gcat[0][col][8 * w + 4 * tl + q][0] = a0[tl];
                *(floatx4*)&gcat[1][col][8 * w + 4 * tl + q][0] = a1[tl];
            }
        }
        __syncthreads();
        // phase 4: one activation set per thread (L1 lags: skip at t==0)
        if (sb && (L == 0 || t > 0)) {
            const floatx4 g = *(const floatx4*)&gcat[L][rr2][kst][0];
            const float gi = sigm(g[0]), gf = sigm(g[1]);
            const float gg = tanhx(g[2]), go = sigm(g[3]);
            c = gf * c + gi * gg;
            const float hv = go * tanhx(c);
            const int k = (L ? H : 0) + kst;
            B2[wb][k >> 5][(k >> 3) & 3][rr2][k & 7] = (_Float16)hv;
        }
        // phase 4b: stage x(t+1) into XS[wb]
        if (xs_act && t + 1 < TT) {
            half4v h;
            h[0] = (_Float16)xl.x; h[1] = (_Float16)xl.y;
            h[2] = (_Float16)xl.z; h[3] = (_Float16)xl.w;
            *(half4v*)&XS[wb][xrow][xc4 * 4] = h;
        }
        __syncthreads();
    }
    // ---- tail: gates1(TT-1) from B2[TT&1] = [h0(TT-1); h1(TT-2); 1.0] ----
    {
        const int rb = TT & 1;
        half8 bf[4];
        #pragma unroll
        for (int s = 0; s < 4; ++s) bf[s] = *(const half8*)&B2[rb][s][q][col][0];
        #pragma unroll
        for (int tl = 0; tl < 2; ++tl) {
            floatx4 a1 = (floatx4)(0.0f);
            #pragma unroll
            for (int s = 0; s < 4; ++s)
                a1 = __builtin_amdgcn_mfma_f32_16x16x32_f16(__builtin_bit_cast(half8, Ap[14+tl*4+s]), bf[s], a1, 0, 0, 0);
            if (col < 2)
                *(floatx4*)&gcat[1][col][8 * w + 4 * tl + q][0] = a1;
        }
        __syncthreads();
        if (sb && L == 1) {
            const floatx4 g = *(const floatx4*)&gcat[1][rr2][kst][0];
            const float gi = sigm(g[0]), gf = sigm(g[1]);
            const float gg = tanhx(g[2]), go = sigm(g[3]);
            c = gf * c + gi * gg;
            h1f[rr2][kst] = go * tanhx(c);
        }
        __syncthreads();
    }
    // ---- fused FC on h1(TT-1): 2 rows x 144 outs ----
    if (tid < 2 * ODIM) {
        const int r = tid / ODIM, o = tid - r * ODIM;
        float s = bfc[o];
        const float* wr = Wfc + (size_t)o * H;
        #pragma unroll
        for (int k = 0; k < H; ++k) s += wr[k] * h1f[r][k];
        out[(size_t)(b0 + r) * ODIM + o] = s;
    }
}

extern "C" void kernel_launch(void* const* d_in, const int* in_sizes, int n_in,
                              void* d_out, int out_size, void* d_ws, size_t ws_size,
                              hipStream_t stream) {
    const float* x    = (const float*)d_in[0];
    const float* wih0 = (const float*)d_in[1];
    const float* whh0 = (const float*)d_in[2];
    const float* bih0 = (const float*)d_in[3];
    const float* bhh0 = (const float*)d_in[4];
    const float* wih1 = (const float*)d_in[5];
    const float* whh1 = (const float*)d_in[6];
    const float* bih1 = (const float*)d_in[7];
    const float* bhh1 = (const float*)d_in[8];
    const float* wfc  = (const float*)d_in[9];
    const float* bfc  = (const float*)d_in[10];
    float* outp = (float*)d_out;

    _Float16* Acat = (_Float16*)d_ws;   // 512 threads x 176 halfs = 180,224 B

    wprep<<<1, 512, 0, stream>>>(whh0, wih0, bih0, bhh0, wih1, whh1, bih1, bhh1, Acat);
    lstm_fused<<<BATCH / 2, 512, 0, stream>>>(x, Acat, wfc, bfc, outp);
}